// Round 6
// baseline (294.573 us; speedup 1.0000x reference)
//
#include <hip/hip_runtime.h>

// MHA: B=4, S=2048, D=1024, H=16, Hd=64, causal. fp32 in/out, bf16 MFMA compute.
// cast (1 dispatch) -> fused QKV gemm (Q scaled, K row-major, V transposed) ->
// flash attn (S^T orientation, K double-buffered in LDS w/ 1 barrier/iter,
// V-frags direct-from-global prefetched, no-running-max softmax) -> out gemm.

typedef float f32x4 __attribute__((ext_vector_type(4)));
typedef short s16x8 __attribute__((ext_vector_type(8)));

#if __has_builtin(__builtin_amdgcn_exp2f)
#define EXP2(x) __builtin_amdgcn_exp2f(x)
#else
#define EXP2(x) exp2f(x)
#endif

// RNE float -> bf16 bits
__device__ __forceinline__ unsigned short f2bf(float f) {
  unsigned int u = __float_as_uint(f);
  u += 0x7fffu + ((u >> 16) & 1u);
  return (unsigned short)(u >> 16);
}

// pack two floats to bf16 pair, round-half-up
__device__ __forceinline__ unsigned int pk2bf(float f0, float f1) {
  return __builtin_amdgcn_perm(__float_as_uint(f1) + 0x8000u,
                               __float_as_uint(f0) + 0x8000u, 0x07060302u);
}

// pack two floats to bf16 pair, TRUNCATING (1 v_perm) — for P only
__device__ __forceinline__ unsigned int pk2bf_t(float f0, float f1) {
  return __builtin_amdgcn_perm(__float_as_uint(f1), __float_as_uint(f0), 0x07060302u);
}

// async global->LDS, 16 bytes per lane (wave-uniform LDS base + lane*16)
__device__ __forceinline__ void gl_lds16(const short* g, short* lds) {
  __builtin_amdgcn_global_load_lds(
      (const __attribute__((address_space(1))) unsigned int*)g,
      (__attribute__((address_space(3))) unsigned int*)lds, 16, 0, 0);
}

// ---------------- fp32 -> bf16 cast: X + all 4 weights, one dispatch ----------------
__global__ __launch_bounds__(256) void cvt_all(const float4* __restrict__ X,
                                               const float4* __restrict__ Wq,
                                               const float4* __restrict__ Wk,
                                               const float4* __restrict__ Wv,
                                               const float4* __restrict__ Wo,
                                               ushort4* __restrict__ xb,
                                               ushort4* __restrict__ wqkv,
                                               ushort4* __restrict__ wob) {
  const int NX = 8192 * 1024 / 4;       // 2,097,152 float4
  const int NW = 1024 * 1024 / 4;       // 262,144 float4 per weight
  const int NT = NX + 4 * NW;
  int i = blockIdx.x * blockDim.x + threadIdx.x;
  int stride = gridDim.x * blockDim.x;
  for (int idx = i; idx < NT; idx += stride) {
    const float4* s;
    ushort4* d;
    int off;
    if (idx < NX) {
      s = X; d = xb; off = idx;
    } else {
      int j = idx - NX;
      int w = j >> 18;
      off = j & (NW - 1);
      switch (w) {
        case 0: s = Wq; d = wqkv; break;
        case 1: s = Wk; d = wqkv + NW; break;
        case 2: s = Wv; d = wqkv + 2 * NW; break;
        default: s = Wo; d = wob; break;
      }
    }
    float4 f = s[off];
    ushort4 r;
    r.x = f2bf(f.x); r.y = f2bf(f.y); r.z = f2bf(f.z); r.w = f2bf(f.w);
    d[off] = r;
  }
}

// ---------------- GEMM: C[M,N] = A[M,K] * B[N,K]^T (both bf16 row-major) ----------------
// MODE 0: fp32 output to Cf.
// MODE 1: QKV mode, N=3072: cols [0,1024) -> q_o (scaled bf16), [1024,2048) -> k_o,
//         [2048,3072) -> vT_o transposed as (b,h,d,s) with packed 8B stores.
template <int MODE>
__global__ __launch_bounds__(256) void gemm_bt(const short* __restrict__ A,
                                               const short* __restrict__ B,
                                               float* __restrict__ Cf,
                                               short* __restrict__ q_o,
                                               short* __restrict__ k_o,
                                               short* __restrict__ vT_o,
                                               int M, int N, int K) {
  const int tid = threadIdx.x;
  const int wave = tid >> 6, lane = tid & 63;
  const int quad = lane >> 4, l15 = lane & 15;
  const int m0 = blockIdx.x * 128, n0 = blockIdx.y * 128;
  const int wm = (wave >> 1) * 64, wn = (wave & 1) * 64;

  __shared__ __align__(16) short As[128 * 64];
  __shared__ __align__(16) short Bs[128 * 64];

  const f32x4 z4 = {0.f, 0.f, 0.f, 0.f};
  f32x4 acc[4][4];
  for (int i = 0; i < 4; ++i)
    for (int j = 0; j < 4; ++j) acc[i][j] = z4;

  for (int k0 = 0; k0 < K; k0 += 64) {
    __syncthreads();
    for (int i = 0; i < 4; ++i) {
      int c = wave * 4 + i;
      int r = c * 8 + (lane >> 3);
      int c8 = (lane & 7) ^ (r & 7);
      gl_lds16(A + (size_t)(m0 + r) * K + k0 + c8 * 8, As + c * 512 + lane * 8);
      gl_lds16(B + (size_t)(n0 + r) * K + k0 + c8 * 8, Bs + c * 512 + lane * 8);
    }
    __syncthreads();
    for (int kk = 0; kk < 64; kk += 32) {
      int c8b = (kk >> 3) + quad;
      s16x8 af[4], bfr[4];
      for (int mt = 0; mt < 4; ++mt) {
        int row = wm + mt * 16 + l15;
        af[mt] = *(const s16x8*)(As + row * 64 + ((c8b ^ (row & 7)) << 3));
      }
      for (int nt = 0; nt < 4; ++nt) {
        int row = wn + nt * 16 + l15;
        bfr[nt] = *(const s16x8*)(Bs + row * 64 + ((c8b ^ (row & 7)) << 3));
      }
      for (int mt = 0; mt < 4; ++mt)
        for (int nt = 0; nt < 4; ++nt)
          acc[mt][nt] = __builtin_amdgcn_mfma_f32_16x16x32_bf16(af[mt], bfr[nt],
                                                                acc[mt][nt], 0, 0, 0);
    }
  }

  if (MODE == 0) {
    for (int mt = 0; mt < 4; ++mt)
      for (int nt = 0; nt < 4; ++nt) {
        int col = n0 + wn + nt * 16 + l15;
        for (int r = 0; r < 4; ++r) {
          int row = m0 + wm + mt * 16 + quad * 4 + r;
          Cf[(size_t)row * N + col] = acc[mt][nt][r];
        }
      }
  } else {
    if (n0 < 1024) {  // Q, fold softmax scale * log2(e)
      const float scale = 0.18033688011112042f;  // 0.125 * log2(e)
      for (int mt = 0; mt < 4; ++mt)
        for (int nt = 0; nt < 4; ++nt) {
          int col = n0 + wn + nt * 16 + l15;
          for (int r = 0; r < 4; ++r) {
            int row = m0 + wm + mt * 16 + quad * 4 + r;
            ((unsigned short*)q_o)[(size_t)row * 1024 + col] = f2bf(acc[mt][nt][r] * scale);
          }
        }
    } else if (n0 < 2048) {  // K
      for (int mt = 0; mt < 4; ++mt)
        for (int nt = 0; nt < 4; ++nt) {
          int col = n0 - 1024 + wn + nt * 16 + l15;
          for (int r = 0; r < 4; ++r) {
            int row = m0 + wm + mt * 16 + quad * 4 + r;
            ((unsigned short*)k_o)[(size_t)row * 1024 + col] = f2bf(acc[mt][nt][r]);
          }
        }
    } else {  // V transposed: vT[((b*16+h)*64+d)*2048 + s], 4 consecutive s per lane
      for (int mt = 0; mt < 4; ++mt)
        for (int nt = 0; nt < 4; ++nt) {
          int col = n0 - 2048 + wn + nt * 16 + l15;
          int h = col >> 6, d = col & 63;
          int row0 = m0 + wm + mt * 16 + quad * 4;
          int b = row0 >> 11, s = row0 & 2047;
          uint2 pk;
          pk.x = pk2bf(acc[mt][nt][0], acc[mt][nt][1]);
          pk.y = pk2bf(acc[mt][nt][2], acc[mt][nt][3]);
          *(uint2*)((unsigned short*)vT_o + (((size_t)b * 16 + h) * 64 + d) * 2048 + s) = pk;
        }
    }
  }
}

// ---------------- flash attention: K dbuf (1 barrier/iter), V direct, heavy-first ----
// grid (64 bh, 16 y): qt = 15 - y (long blocks dispatch first). 4 waves x 32 q-rows.
// Per iter: barrier (K(t) DMA done a full iter ago -> ~zero drain); prefetch V kk=0
// frags (issued before K(t+1) DMA so their waitcnt doesn't drain it); stage K(t+1)
// into alternate buffer; S^T = K*Q^T from LDS; exp2 softmax (no running max, scores
// pre-scaled); P per-wave LDS round-trip; PV with V-frags pipelined from global.
__global__ __launch_bounds__(256, 3) void attn_kernel(const short* __restrict__ qb,
                                                      const short* __restrict__ kb,
                                                      const short* __restrict__ vT,
                                                      short* __restrict__ ob) {
  const int bh = blockIdx.x;
  const int qt = 15 - (int)blockIdx.y;
  const int tid = threadIdx.x;
  const int wave = tid >> 6, lane = tid & 63;
  const int quad = lane >> 4, l15 = lane & 15;
  const int q0 = qt * 128;
  const size_t rowbase = (size_t)(bh >> 4) * 2048;
  const int hoff = (bh & 15) * 64;

  __shared__ __align__(16) short Ks[2][8192];  // 128 kv x 64 d, swizzled, dbuf (32 KB)
  __shared__ __align__(16) short Ps[10240];    // per-wave P chunks, 2x(32q x 40) (20 KB)
  short* Pw = Ps + wave * 2560;

  // staging coords (per wave stages rows [wave*32, wave*32+32) of the K tile)
  const int sc = wave * 4;
  const int sr0 = sc * 8 + (lane >> 3);
  const int sc8 = (lane & 7);

  // Q B-frags (resident all kernel): lane(q=l15, d=quad*8+j)
  s16x8 qf[2][2];
#pragma unroll
  for (int n = 0; n < 2; ++n) {
    const short* qrow = qb + (rowbase + q0 + wave * 32 + n * 16 + l15) * 1024 + hoff;
#pragma unroll
    for (int k2 = 0; k2 < 2; ++k2)
      qf[n][k2] = *(const s16x8*)(qrow + k2 * 32 + quad * 8);
  }

  // prologue: stage K(0) into Ks[0]
#pragma unroll
  for (int i = 0; i < 4; ++i) {
    int r = sr0 + i * 8;
    int c8 = sc8 ^ (r & 7);
    gl_lds16(kb + (rowbase + r) * 1024 + hoff + c8 * 8, Ks[0] + (sc + i) * 512 + lane * 8);
  }

  const f32x4 z4 = {0.f, 0.f, 0.f, 0.f};
  f32x4 oacc[2][4];  // O^T: [q-half n][d-tile], row=d=quad*4+r, col=q=l15
#pragma unroll
  for (int n = 0; n < 2; ++n)
#pragma unroll
    for (int dt = 0; dt < 4; ++dt) oacc[n][dt] = z4;
  float lacc[2] = {0.f, 0.f};  // per-lane partial row-sums

  const short* vbase = vT + ((size_t)bh * 64 + l15) * 2048 + quad * 8;

  for (int t = 0; t <= qt; ++t) {
    __syncthreads();  // K(t) visible (DMA issued a full iter ago); buffer reuse safe

    const short* vt = vbase + t * 128;
    // prefetch V kk=0 frags FIRST (oldest in vmcnt queue -> their wait won't drain DMA)
    s16x8 vf0[4], vf1[4];
#pragma unroll
    for (int dt = 0; dt < 4; ++dt) vf0[dt] = *(const s16x8*)(vt + dt * 16 * 2048);

    if (t < qt) {  // stage K(t+1) into alternate buffer; full iter to complete
      short* kn = Ks[(t + 1) & 1];
#pragma unroll
      for (int i = 0; i < 4; ++i) {
        int r = sr0 + i * 8;
        int c8 = sc8 ^ (r & 7);
        gl_lds16(kb + (rowbase + (t + 1) * 128 + r) * 1024 + hoff + c8 * 8,
                 kn + (sc + i) * 512 + lane * 8);
      }
    }

    const short* Kc = Ks[t & 1];

    // S^T = K * Q^T : sacc[n][m], row=kv=m*16+quad*4+r, col=q=n*16+l15
    f32x4 sacc[2][8];
#pragma unroll
    for (int n = 0; n < 2; ++n)
#pragma unroll
      for (int m = 0; m < 8; ++m) sacc[n][m] = z4;
#pragma unroll
    for (int k2 = 0; k2 < 2; ++k2) {
#pragma unroll
      for (int m = 0; m < 8; ++m) {
        int row = m * 16 + l15;
        s16x8 kf = *(const s16x8*)(Kc + row * 64 + ((((k2 << 2) + quad) ^ (row & 7)) << 3));
        sacc[0][m] = __builtin_amdgcn_mfma_f32_16x16x32_bf16(kf, qf[0][k2], sacc[0][m], 0, 0, 0);
        sacc[1][m] = __builtin_amdgcn_mfma_f32_16x16x32_bf16(kf, qf[1][k2], sacc[1][m], 0, 0, 0);
      }
    }

    if (t == qt) {  // causal mask on diagonal tile
#pragma unroll
      for (int n = 0; n < 2; ++n) {
        int qg = wave * 32 + n * 16 + l15;
#pragma unroll
        for (int m = 0; m < 8; ++m) {
          int kvb = m * 16 + quad * 4;
#pragma unroll
          for (int r = 0; r < 4; ++r)
            if (kvb + r > qg) sacc[n][m][r] = -1e30f;
        }
      }
    }

    // softmax without running max: P = exp2(S), per-lane l accumulation
    uint2 pp[2][8];  // P packed bf16 (truncating), [n][m]: kv=m*16+quad*4+{0..3}
#pragma unroll
    for (int n = 0; n < 2; ++n) {
      float sum = 0.f;
#pragma unroll
      for (int m = 0; m < 8; ++m) {
        float p0 = EXP2(sacc[n][m][0]);
        float p1 = EXP2(sacc[n][m][1]);
        float p2 = EXP2(sacc[n][m][2]);
        float p3 = EXP2(sacc[n][m][3]);
        sum += (p0 + p1) + (p2 + p3);
        pp[n][m].x = pk2bf_t(p0, p1);
        pp[n][m].y = pk2bf_t(p2, p3);
      }
      lacc[n] += sum;
    }

    // O^T += V^T * P^T, kv chunks of 32; P via per-wave LDS; V-frags pipelined
#pragma unroll
    for (int kk = 0; kk < 4; ++kk) {
      s16x8* vc = (kk & 1) ? vf1 : vf0;
      if (kk < 3) {  // prefetch next kk's V frags under this kk's LDS+MFMA work
        s16x8* vn = (kk & 1) ? vf0 : vf1;
#pragma unroll
        for (int dt = 0; dt < 4; ++dt)
          vn[dt] = *(const s16x8*)(vt + dt * 16 * 2048 + (kk + 1) * 32);
      }
      short* Pb = Pw + (kk & 1) * 1280;
#pragma unroll
      for (int n = 0; n < 2; ++n)
#pragma unroll
        for (int mm = 0; mm < 2; ++mm)
          *(uint2*)(Pb + (n * 16 + l15) * 40 + mm * 16 + quad * 4) = pp[n][2 * kk + mm];
      s16x8 pf0 = *(const s16x8*)(Pb + l15 * 40 + quad * 8);
      s16x8 pf1 = *(const s16x8*)(Pb + (16 + l15) * 40 + quad * 8);
#pragma unroll
      for (int dt = 0; dt < 4; ++dt) {
        oacc[0][dt] = __builtin_amdgcn_mfma_f32_16x16x32_bf16(vc[dt], pf0, oacc[0][dt], 0, 0, 0);
        oacc[1][dt] = __builtin_amdgcn_mfma_f32_16x16x32_bf16(vc[dt], pf1, oacc[1][dt], 0, 0, 0);
      }
    }
  }

  // epilogue: reduce l across quads, normalize, store row-major O (8B stores)
#pragma unroll
  for (int n = 0; n < 2; ++n) {
    float l = lacc[n];
    l += __shfl_xor(l, 16);
    l += __shfl_xor(l, 32);
    float inv = 1.0f / l;
    size_t row = rowbase + q0 + wave * 32 + n * 16 + l15;
    unsigned short* orow = (unsigned short*)ob + row * 1024 + hoff;
#pragma unroll
    for (int dt = 0; dt < 4; ++dt) {
      f32x4 v = oacc[n][dt];
      uint2 pk;
      pk.x = pk2bf(v[0] * inv, v[1] * inv);
      pk.y = pk2bf(v[2] * inv, v[3] * inv);
      *(uint2*)(orow + dt * 16 + quad * 4) = pk;
    }
  }
}

extern "C" void kernel_launch(void* const* d_in, const int* in_sizes, int n_in,
                              void* d_out, int out_size, void* d_ws, size_t ws_size,
                              hipStream_t stream) {
  const float* X  = (const float*)d_in[0];
  const float* Wq = (const float*)d_in[1];
  const float* Wk = (const float*)d_in[2];
  const float* Wv = (const float*)d_in[3];
  const float* Wo = (const float*)d_in[4];

  // workspace (bf16 shorts), 72 MB total; ob aliases xb (dead after QKV gemm)
  short* xb   = (short*)d_ws;                    // 8192x1024 (16 MB)
  short* wqkv = xb + (size_t)8192 * 1024;        // 3072x1024 ( 6 MB)
  short* wob  = wqkv + (size_t)3072 * 1024;      // 1024x1024 ( 2 MB)
  short* qb   = wob + (size_t)1024 * 1024;       // 8192x1024 (16 MB)
  short* kb   = qb + (size_t)8192 * 1024;        // 8192x1024 (16 MB)
  short* vT   = kb + (size_t)8192 * 1024;        // (4,16,64,2048) (16 MB)
  short* ob   = xb;

  const int MB = 8192;

  cvt_all<<<3072, 256, 0, stream>>>((const float4*)X, (const float4*)Wq, (const float4*)Wk,
                                    (const float4*)Wv, (const float4*)Wo, (ushort4*)xb,
                                    (ushort4*)wqkv, (ushort4*)wob);

  // fused QKV projection -> qb (scaled), kb, vT
  gemm_bt<1><<<dim3(64, 24), 256, 0, stream>>>(xb, wqkv, nullptr, qb, kb, vT, MB, 3072, 1024);

  // flash attention -> ob (bf16)
  attn_kernel<<<dim3(64, 16), 256, 0, stream>>>(qb, kb, vT, ob);

  // output projection -> fp32 d_out
  gemm_bt<0><<<dim3(64, 8), 256, 0, stream>>>(ob, wob, (float*)d_out, nullptr, nullptr,
                                              nullptr, MB, 1024, 1024);
}

// Round 7
// 242.319 us; speedup vs baseline: 1.2156x; 1.2156x over previous
//
#include <hip/hip_runtime.h>

// MHA: B=4, S=2048, D=1024, H=16, Hd=64, causal. fp32 in/out, bf16 MFMA compute.
// cast -> fused QKV gemm (Q scaled, K row-major, V transposed) -> flash attn
// (32x32x16 MFMA, K+V^T double-buffered LDS w/ 1 barrier/iter, P exchanged via
// shfl_xor(32) in registers — no P LDS round-trip) -> out gemm.

typedef float f32x4 __attribute__((ext_vector_type(4)));
typedef float f32x16 __attribute__((ext_vector_type(16)));
typedef short s16x8 __attribute__((ext_vector_type(8)));

#if __has_builtin(__builtin_amdgcn_exp2f)
#define EXP2(x) __builtin_amdgcn_exp2f(x)
#else
#define EXP2(x) exp2f(x)
#endif

// RNE float -> bf16 bits
__device__ __forceinline__ unsigned short f2bf(float f) {
  unsigned int u = __float_as_uint(f);
  u += 0x7fffu + ((u >> 16) & 1u);
  return (unsigned short)(u >> 16);
}

// pack two floats to bf16 pair, round-half-up
__device__ __forceinline__ unsigned int pk2bf(float f0, float f1) {
  return __builtin_amdgcn_perm(__float_as_uint(f1) + 0x8000u,
                               __float_as_uint(f0) + 0x8000u, 0x07060302u);
}

// pack two floats to bf16 pair, TRUNCATING (1 v_perm) — for P only
__device__ __forceinline__ unsigned int pk2bf_t(float f0, float f1) {
  return __builtin_amdgcn_perm(__float_as_uint(f1), __float_as_uint(f0), 0x07060302u);
}

// async global->LDS, 16 bytes per lane (wave-uniform LDS base + lane*16)
__device__ __forceinline__ void gl_lds16(const short* g, short* lds) {
  __builtin_amdgcn_global_load_lds(
      (const __attribute__((address_space(1))) unsigned int*)g,
      (__attribute__((address_space(3))) unsigned int*)lds, 16, 0, 0);
}

// ---------------- fp32 -> bf16 cast: X + all 4 weights, one dispatch ----------------
__global__ __launch_bounds__(256) void cvt_all(const float4* __restrict__ X,
                                               const float4* __restrict__ Wq,
                                               const float4* __restrict__ Wk,
                                               const float4* __restrict__ Wv,
                                               const float4* __restrict__ Wo,
                                               ushort4* __restrict__ xb,
                                               ushort4* __restrict__ wqkv,
                                               ushort4* __restrict__ wob) {
  const int NX = 8192 * 1024 / 4;
  const int NW = 1024 * 1024 / 4;
  const int NT = NX + 4 * NW;
  int i = blockIdx.x * blockDim.x + threadIdx.x;
  int stride = gridDim.x * blockDim.x;
  for (int idx = i; idx < NT; idx += stride) {
    const float4* s;
    ushort4* d;
    int off;
    if (idx < NX) {
      s = X; d = xb; off = idx;
    } else {
      int j = idx - NX;
      int w = j >> 18;
      off = j & (NW - 1);
      switch (w) {
        case 0: s = Wq; d = wqkv; break;
        case 1: s = Wk; d = wqkv + NW; break;
        case 2: s = Wv; d = wqkv + 2 * NW; break;
        default: s = Wo; d = wob; break;
      }
    }
    float4 f = s[off];
    ushort4 r;
    r.x = f2bf(f.x); r.y = f2bf(f.y); r.z = f2bf(f.z); r.w = f2bf(f.w);
    d[off] = r;
  }
}

// ---------------- GEMM: C[M,N] = A[M,K] * B[N,K]^T (both bf16 row-major) ----------------
// MODE 0: fp32 output to Cf.
// MODE 1: QKV mode, N=3072: cols [0,1024) -> q_o (scaled bf16), [1024,2048) -> k_o,
//         [2048,3072) -> vT_o transposed as (b,h,d,s) with packed 8B stores.
template <int MODE>
__global__ __launch_bounds__(256) void gemm_bt(const short* __restrict__ A,
                                               const short* __restrict__ B,
                                               float* __restrict__ Cf,
                                               short* __restrict__ q_o,
                                               short* __restrict__ k_o,
                                               short* __restrict__ vT_o,
                                               int M, int N, int K) {
  const int tid = threadIdx.x;
  const int wave = tid >> 6, lane = tid & 63;
  const int quad = lane >> 4, l15 = lane & 15;
  const int m0 = blockIdx.x * 128, n0 = blockIdx.y * 128;
  const int wm = (wave >> 1) * 64, wn = (wave & 1) * 64;

  __shared__ __align__(16) short As[128 * 64];
  __shared__ __align__(16) short Bs[128 * 64];

  const f32x4 z4 = {0.f, 0.f, 0.f, 0.f};
  f32x4 acc[4][4];
  for (int i = 0; i < 4; ++i)
    for (int j = 0; j < 4; ++j) acc[i][j] = z4;

  for (int k0 = 0; k0 < K; k0 += 64) {
    __syncthreads();
    for (int i = 0; i < 4; ++i) {
      int c = wave * 4 + i;
      int r = c * 8 + (lane >> 3);
      int c8 = (lane & 7) ^ (r & 7);
      gl_lds16(A + (size_t)(m0 + r) * K + k0 + c8 * 8, As + c * 512 + lane * 8);
      gl_lds16(B + (size_t)(n0 + r) * K + k0 + c8 * 8, Bs + c * 512 + lane * 8);
    }
    __syncthreads();
    for (int kk = 0; kk < 64; kk += 32) {
      int c8b = (kk >> 3) + quad;
      s16x8 af[4], bfr[4];
      for (int mt = 0; mt < 4; ++mt) {
        int row = wm + mt * 16 + l15;
        af[mt] = *(const s16x8*)(As + row * 64 + ((c8b ^ (row & 7)) << 3));
      }
      for (int nt = 0; nt < 4; ++nt) {
        int row = wn + nt * 16 + l15;
        bfr[nt] = *(const s16x8*)(Bs + row * 64 + ((c8b ^ (row & 7)) << 3));
      }
      for (int mt = 0; mt < 4; ++mt)
        for (int nt = 0; nt < 4; ++nt)
          acc[mt][nt] = __builtin_amdgcn_mfma_f32_16x16x32_bf16(af[mt], bfr[nt],
                                                                acc[mt][nt], 0, 0, 0);
    }
  }

  if (MODE == 0) {
    for (int mt = 0; mt < 4; ++mt)
      for (int nt = 0; nt < 4; ++nt) {
        int col = n0 + wn + nt * 16 + l15;
        for (int r = 0; r < 4; ++r) {
          int row = m0 + wm + mt * 16 + quad * 4 + r;
          Cf[(size_t)row * N + col] = acc[mt][nt][r];
        }
      }
  } else {
    if (n0 < 1024) {  // Q, fold softmax scale * log2(e)
      const float scale = 0.18033688011112042f;  // 0.125 * log2(e)
      for (int mt = 0; mt < 4; ++mt)
        for (int nt = 0; nt < 4; ++nt) {
          int col = n0 + wn + nt * 16 + l15;
          for (int r = 0; r < 4; ++r) {
            int row = m0 + wm + mt * 16 + quad * 4 + r;
            ((unsigned short*)q_o)[(size_t)row * 1024 + col] = f2bf(acc[mt][nt][r] * scale);
          }
        }
    } else if (n0 < 2048) {  // K
      for (int mt = 0; mt < 4; ++mt)
        for (int nt = 0; nt < 4; ++nt) {
          int col = n0 - 1024 + wn + nt * 16 + l15;
          for (int r = 0; r < 4; ++r) {
            int row = m0 + wm + mt * 16 + quad * 4 + r;
            ((unsigned short*)k_o)[(size_t)row * 1024 + col] = f2bf(acc[mt][nt][r]);
          }
        }
    } else {  // V transposed: vT[((b*16+h)*64+d)*2048 + s], 4 consecutive s per lane
      for (int mt = 0; mt < 4; ++mt)
        for (int nt = 0; nt < 4; ++nt) {
          int col = n0 - 2048 + wn + nt * 16 + l15;
          int h = col >> 6, d = col & 63;
          int row0 = m0 + wm + mt * 16 + quad * 4;
          int b = row0 >> 11, s = row0 & 2047;
          uint2 pk;
          pk.x = pk2bf(acc[mt][nt][0], acc[mt][nt][1]);
          pk.y = pk2bf(acc[mt][nt][2], acc[mt][nt][3]);
          *(uint2*)((unsigned short*)vT_o + (((size_t)b * 16 + h) * 64 + d) * 2048 + s) = pk;
        }
    }
  }
}

// ---------------- flash attention: 32x32 MFMA, dbuf staging, register-P ----------------
// grid (64 bh, 16 y): qt = 15 - y (heavy blocks dispatch first). 4 waves x 32 q each.
// Lane holds ONE q column (l31) in S^T C-layout -> softmax per-lane, l reduced with a
// single shfl_xor(32). P^T B-frags for PV built from registers with one uint2
// shfl_xor(32) exchange per 16-kv step. K/V^T double-buffered: DMA for t+1 issued
// right after the single per-iter barrier -> full iteration to complete (no drain).
__global__ __launch_bounds__(256, 2) void attn_kernel(const short* __restrict__ qb,
                                                      const short* __restrict__ kb,
                                                      const short* __restrict__ vT,
                                                      short* __restrict__ ob) {
  const int bh = blockIdx.x;
  const int qt = 15 - (int)blockIdx.y;
  const int tid = threadIdx.x;
  const int wave = tid >> 6, lane = tid & 63;
  const int l31 = lane & 31, h = lane >> 5;
  const int q0 = qt * 128;
  const size_t rowbase = (size_t)(bh >> 4) * 2048;
  const int hoff = (bh & 15) * 64;

  __shared__ __align__(16) short Ks[2][8192];   // 128 kv x 64 d, swizzled (32 KB)
  __shared__ __align__(16) short VTs[2][8192];  // 64 d x 128 kv, swizzled (32 KB)

  // staging coords: chunks c = wave*4+i, 512 shorts each
  const int kc = wave * 4;
  const int kr = kc * 8 + (lane >> 3);            // K row (8 rows per chunk)
  const short* ksrc = kb + (rowbase + kr) * 1024 + hoff + (((lane & 7) ^ (kr & 7)) << 3);
  const int vg = lane & 15;
  const short* vsrc_i[4];
#pragma unroll
  for (int i = 0; i < 4; ++i) {
    int d = (kc + i) * 4 + (lane >> 4);           // V^T d-row (4 rows per chunk)
    vsrc_i[i] = vT + ((size_t)bh * 64 + d) * 2048 + ((vg ^ (d & 7)) << 3);
  }

  // Q B-frags: lane(q=l31, d = ks*16 + h*8 + j)
  s16x8 qf[4];
  {
    const short* qrow = qb + (rowbase + q0 + wave * 32 + l31) * 1024 + hoff + h * 8;
#pragma unroll
    for (int k = 0; k < 4; ++k) qf[k] = *(const s16x8*)(qrow + k * 16);
  }

  // prologue: stage t=0 into buffer 0
#pragma unroll
  for (int i = 0; i < 4; ++i)
    gl_lds16(ksrc + i * 8 * 1024, Ks[0] + (kc + i) * 512 + lane * 8);
#pragma unroll
  for (int i = 0; i < 4; ++i)
    gl_lds16(vsrc_i[i], VTs[0] + (kc + i) * 512 + lane * 8);

  f32x16 oacc[2];  // O^T: [d-tile], col=q=l31, row_d=(e&3)+8*(e>>2)+4h+32dt
#pragma unroll
  for (int dt = 0; dt < 2; ++dt)
#pragma unroll
    for (int e = 0; e < 16; ++e) oacc[dt][e] = 0.f;
  float lacc = 0.f;
  const int kswz = l31 & 7;

  for (int t = 0; t <= qt; ++t) {
    __syncthreads();  // drains DMA(t) (issued a full iter ago); LDS reads of old buf done
    const int cur = t & 1;

    if (t < qt) {  // stage t+1 into alternate buffers; whole iteration to complete
      const int nxt = cur ^ 1;
      const short* ks = ksrc + (size_t)(t + 1) * 128 * 1024;
#pragma unroll
      for (int i = 0; i < 4; ++i)
        gl_lds16(ks + i * 8 * 1024, Ks[nxt] + (kc + i) * 512 + lane * 8);
#pragma unroll
      for (int i = 0; i < 4; ++i)
        gl_lds16(vsrc_i[i] + (t + 1) * 128, VTs[nxt] + (kc + i) * 512 + lane * 8);
    }

    const short* Kc = Ks[cur];
    const short* Vc = VTs[cur];

    // S^T = K * Q^T, 4 m-tiles of 32 kv, computed in 2 groups to bound registers.
    // C-layout: col=q=l31, row_kv=(e&3)+8*(e>>2)+4h (+32m). Then exp2 + pack to pp.
    unsigned int pp[4][8];  // P bf16 pairs: pp[m][rg] = (reg 2rg, reg 2rg+1)
    float sum = 0.f;
#pragma unroll
    for (int g = 0; g < 2; ++g) {
      f32x16 s0, s1;
#pragma unroll
      for (int e = 0; e < 16; ++e) { s0[e] = 0.f; s1[e] = 0.f; }
#pragma unroll
      for (int ks = 0; ks < 4; ++ks) {
        int pos = ((ks << 1) + h) ^ kswz;
        s16x8 kf0 = *(const s16x8*)(Kc + ((2 * g) * 32 + l31) * 64 + (pos << 3));
        s16x8 kf1 = *(const s16x8*)(Kc + ((2 * g + 1) * 32 + l31) * 64 + (pos << 3));
        s0 = __builtin_amdgcn_mfma_f32_32x32x16_bf16(kf0, qf[ks], s0, 0, 0, 0);
        s1 = __builtin_amdgcn_mfma_f32_32x32x16_bf16(kf1, qf[ks], s1, 0, 0, 0);
      }
      if (t == qt) {  // causal mask on diagonal tile (local compare: t*128 == q0)
        int qg = wave * 32 + l31;
#pragma unroll
        for (int e = 0; e < 16; ++e) {
          int rloc = (e & 3) + 8 * (e >> 2) + 4 * h;
          if ((2 * g) * 32 + rloc > qg) s0[e] = -1e30f;
          if ((2 * g + 1) * 32 + rloc > qg) s1[e] = -1e30f;
        }
      }
#pragma unroll
      for (int rg = 0; rg < 8; ++rg) {
        float a0 = EXP2(s0[2 * rg]), a1 = EXP2(s0[2 * rg + 1]);
        float b0 = EXP2(s1[2 * rg]), b1 = EXP2(s1[2 * rg + 1]);
        sum += (a0 + a1) + (b0 + b1);
        pp[2 * g][rg] = pk2bf_t(a0, a1);
        pp[2 * g + 1][rg] = pk2bf_t(b0, b1);
      }
    }
    lacc += sum;

    // O^T += V^T * P^T. B-frag(kv step s): lane(q=l31, kv=s*16+h*8+j).
    // Rows 4h-interleave -> one uint2 shfl_xor(32) exchange + selects per step.
#pragma unroll
    for (int s = 0; s < 8; ++s) {
      int m = s >> 1, base = (s & 1) * 4;
      unsigned int ax = pp[m][base + 0], ay = pp[m][base + 1];
      unsigned int bx = pp[m][base + 2], by = pp[m][base + 3];
      unsigned int sx = h ? ax : bx, sy = h ? ay : by;
      unsigned int rx = (unsigned int)__shfl_xor((int)sx, 32);
      unsigned int ry = (unsigned int)__shfl_xor((int)sy, 32);
      union { s16x8 v; unsigned int u[4]; } pf;
      pf.u[0] = h ? rx : ax;
      pf.u[1] = h ? ry : ay;
      pf.u[2] = h ? bx : rx;
      pf.u[3] = h ? by : ry;
#pragma unroll
      for (int dt = 0; dt < 2; ++dt) {
        int d = dt * 32 + l31;
        s16x8 vf = *(const s16x8*)(Vc + d * 128 + ((((s << 1) + h) ^ (d & 7)) << 3));
        oacc[dt] = __builtin_amdgcn_mfma_f32_32x32x16_bf16(vf, pf.v, oacc[dt], 0, 0, 0);
      }
    }
  }

  // epilogue: l across the two half-lanes, normalize, store O rows (8B stores)
  lacc += __shfl_xor(lacc, 32);
  float inv = 1.0f / lacc;
  size_t row = rowbase + q0 + wave * 32 + l31;
  unsigned short* orow = (unsigned short*)ob + row * 1024 + hoff;
#pragma unroll
  for (int dt = 0; dt < 2; ++dt)
#pragma unroll
    for (int rg = 0; rg < 4; ++rg) {
      int d = dt * 32 + rg * 8 + 4 * h;
      uint2 pk;
      pk.x = pk2bf(oacc[dt][rg * 4 + 0] * inv, oacc[dt][rg * 4 + 1] * inv);
      pk.y = pk2bf(oacc[dt][rg * 4 + 2] * inv, oacc[dt][rg * 4 + 3] * inv);
      *(uint2*)(orow + d) = pk;
    }
}

extern "C" void kernel_launch(void* const* d_in, const int* in_sizes, int n_in,
                              void* d_out, int out_size, void* d_ws, size_t ws_size,
                              hipStream_t stream) {
  const float* X  = (const float*)d_in[0];
  const float* Wq = (const float*)d_in[1];
  const float* Wk = (const float*)d_in[2];
  const float* Wv = (const float*)d_in[3];
  const float* Wo = (const float*)d_in[4];

  // workspace (bf16 shorts), 72 MB total; ob aliases xb (dead after QKV gemm)
  short* xb   = (short*)d_ws;                    // 8192x1024 (16 MB)
  short* wqkv = xb + (size_t)8192 * 1024;        // 3072x1024 ( 6 MB)
  short* wob  = wqkv + (size_t)3072 * 1024;      // 1024x1024 ( 2 MB)
  short* qb   = wob + (size_t)1024 * 1024;       // 8192x1024 (16 MB)
  short* kb   = qb + (size_t)8192 * 1024;        // 8192x1024 (16 MB)
  short* vT   = kb + (size_t)8192 * 1024;        // (4,16,64,2048) (16 MB)
  short* ob   = xb;

  const int MB = 8192;

  cvt_all<<<3072, 256, 0, stream>>>((const float4*)X, (const float4*)Wq, (const float4*)Wk,
                                    (const float4*)Wv, (const float4*)Wo, (ushort4*)xb,
                                    (ushort4*)wqkv, (ushort4*)wob);

  // fused QKV projection -> qb (scaled), kb, vT
  gemm_bt<1><<<dim3(64, 24), 256, 0, stream>>>(xb, wqkv, nullptr, qb, kb, vT, MB, 3072, 1024);

  // flash attention -> ob (bf16)
  attn_kernel<<<dim3(64, 16), 256, 0, stream>>>(qb, kb, vT, ob);

  // output projection -> fp32 d_out
  gemm_bt<0><<<dim3(64, 8), 256, 0, stream>>>(ob, wob, (float*)d_out, nullptr, nullptr,
                                              nullptr, MB, 1024, 1024);
}